// Round 1
// baseline (232.463 us; speedup 1.0000x reference)
//
#include <hip/hip_runtime.h>
#include <hip/hip_bf16.h>

typedef unsigned short ushort_t;
typedef unsigned short ushortx8 __attribute__((ext_vector_type(8)));
typedef __bf16        bf16x8   __attribute__((ext_vector_type(8)));
typedef float         f32x4    __attribute__((ext_vector_type(4)));

#define SCALE_Q 0.29730177875068026f   /* 128^-0.25 */
#define LOG2E   1.4426950408889634f
#define OUT_HALF 2097152               /* B*C*H*W elements */

// ---------------------------------------------------------------------------
// pe [n][d][h] f32  ->  pet [h][n][d] f32
__global__ __launch_bounds__(256) void pet_kernel(const float* __restrict__ pe,
                                                  float* __restrict__ pet) {
    int idx = blockIdx.x * 256 + threadIdx.x;     // over n*d = 262144
    if (idx >= 4096 * 64) return;
    float2 p2 = *(const float2*)(pe + (size_t)idx * 2);
    pet[idx]                      = p2.x;         // h = 0 plane
    pet[(size_t)4096 * 64 + idx]  = p2.y;         // h = 1 plane
}

// ---------------------------------------------------------------------------
// QKV projection. grid (64 ntile, 4 b, 3 proj), 256 thr.
// q,k -> token-major bf16 [bh][n][d]; v -> d-major bf16 [bh][d][n].
// q gets (+pe)*scale folded in.
__global__ __launch_bounds__(256) void proj_kernel(
    const float* __restrict__ x,
    const float* __restrict__ wq, const float* __restrict__ bq,
    const float* __restrict__ wk, const float* __restrict__ bk,
    const float* __restrict__ wv, const float* __restrict__ bv,
    const float* __restrict__ pet,
    ushort_t* __restrict__ qw, ushort_t* __restrict__ kw,
    ushort_t* __restrict__ vw)
{
    const int nt = blockIdx.x;         // token tile (64 tokens)
    const int b  = blockIdx.y;
    const int p  = blockIdx.z;         // 0=q 1=k 2=v
    const float* w    = (p == 0) ? wq : (p == 1) ? wk : wv;
    const float* bias = (p == 0) ? bq : (p == 1) ? bk : bv;

    __shared__ __align__(16) union { float xs[128][64]; float tr[128][65]; } sm;

    const int t = threadIdx.x;
    for (int f = t; f < 2048; f += 256) {          // 128c x 64n floats / 4
        int c = f >> 4, pos = (f & 15) << 2;
        *(float4*)(&sm.xs[c][pos]) =
            *(const float4*)(x + ((size_t)(b * 128 + c)) * 4096 + nt * 64 + pos);
    }
    __syncthreads();

    const int lane  = t & 63;
    const int wvid  = __builtin_amdgcn_readfirstlane(t >> 6);
    const int obase = wvid * 32;

    float acc[32];
#pragma unroll
    for (int i = 0; i < 32; ++i) acc[i] = bias[obase + i];

    for (int c0 = 0; c0 < 128; c0 += 16) {
        float xv[16];
#pragma unroll
        for (int cc = 0; cc < 16; ++cc) xv[cc] = sm.xs[c0 + cc][lane];
#pragma unroll
        for (int i = 0; i < 32; ++i) {
            const float* wrow = w + (size_t)(obase + i) * 128 + c0;
#pragma unroll
            for (int cc = 0; cc < 16; ++cc) acc[i] += wrow[cc] * xv[cc];
        }
    }

    if (p == 2) {                       // V: direct d-major coalesced store
#pragma unroll
        for (int i = 0; i < 32; ++i) {
            int o = obase + i, h = o >> 6, d = o & 63;
            __hip_bfloat16 hb = __float2bfloat16(acc[i]);
            vw[(((size_t)(b * 2 + h)) * 64 + d) * 4096 + nt * 64 + lane] =
                __builtin_bit_cast(unsigned short, hb);
        }
        return;
    }

    __syncthreads();                    // xs dead, reuse as f32 transpose buf
#pragma unroll
    for (int i = 0; i < 32; ++i) sm.tr[obase + i][lane] = acc[i];
    __syncthreads();

    ushort_t* dst = (p == 0) ? qw : kw;
    const int n = t >> 2, oq = t & 3;
    const int h = oq >> 1, nglob = nt * 64 + n;
    const int dbase = (oq & 1) * 32;
    ushortx8 u[4];
#pragma unroll
    for (int i = 0; i < 32; ++i) {
        float v = sm.tr[oq * 32 + i][n];
        if (p == 0)
            v = (v + pet[((size_t)h * 4096 + nglob) * 64 + dbase + i]) * SCALE_Q;
        __hip_bfloat16 hb = __float2bfloat16(v);
        u[i >> 3][i & 7] = __builtin_bit_cast(unsigned short, hb);
    }
    size_t base = (((size_t)(b * 2 + h)) * 4096 + nglob) * 64 + dbase;
#pragma unroll
    for (int j = 0; j < 4; ++j) *(ushortx8*)(dst + base + j * 8) = u[j];
}

// ---------------------------------------------------------------------------
// Flash attention. grid (64 qtile, 8 bh), 256 thr (4 waves x 16 q-rows).
__global__ __launch_bounds__(256) void attn_kernel(
    const ushort_t* __restrict__ qw, const ushort_t* __restrict__ kw,
    const ushort_t* __restrict__ vw, float* __restrict__ out)
{
    const int qt = blockIdx.x;          // 0..63
    const int bh = blockIdx.y;          // 0..7
    const int b = bh >> 1, h = bh & 1;
    const int t = threadIdx.x;
    const int lane = t & 63;
    const int wvid = t >> 6;
    const int l16 = lane & 15, lhi = lane >> 4;

    __shared__ __align__(16) union {
        struct { ushort_t Kt[64][72]; ushort_t Vt[64][72]; } kv;
        float Ob[64][65];
    } sm;
    __shared__ __align__(16) ushort_t Pt[4][16][72];

    // Q fragments, resident in regs for the whole kernel
    const ushort_t* qp =
        qw + (((size_t)bh * 4096) + qt * 64 + wvid * 16 + l16) * 64 + lhi * 8;
    const bf16x8 aq0 = __builtin_bit_cast(bf16x8, *(const ushortx8*)(qp));
    const bf16x8 aq1 = __builtin_bit_cast(bf16x8, *(const ushortx8*)(qp + 32));

    float m_r[4], l_r[4];
    f32x4 oacc[4];
    const f32x4 fzero = {0.f, 0.f, 0.f, 0.f};
#pragma unroll
    for (int r = 0; r < 4; ++r) { m_r[r] = -3.0e38f; l_r[r] = 0.f; }
#pragma unroll
    for (int dc = 0; dc < 4; ++dc) oacc[dc] = fzero;

    const ushort_t* kgb = kw + ((size_t)bh * 4096) * 64;
    const ushort_t* vgb = vw + ((size_t)bh * 64) * 4096;

    for (int kt = 0; kt < 64; ++kt) {
        const ushort_t* kg = kgb + (size_t)kt * 64 * 64;
        const ushort_t* vg = vgb + kt * 64;
        for (int c = t; c < 512; c += 256) {
            int row = c >> 3, off = (c & 7) << 3;
            *(ushortx8*)(&sm.kv.Kt[row][off]) =
                *(const ushortx8*)(kg + row * 64 + off);
            *(ushortx8*)(&sm.kv.Vt[row][off]) =
                *(const ushortx8*)(vg + (size_t)row * 4096 + off);
        }
        __syncthreads();

        // S = Q K^T : rows = wave's 16 q, cols = 64 keys
        f32x4 sacc[4];
#pragma unroll
        for (int kc = 0; kc < 4; ++kc) {
            bf16x8 b0 = __builtin_bit_cast(bf16x8,
                *(const ushortx8*)(&sm.kv.Kt[kc * 16 + l16][lhi * 8]));
            bf16x8 b1 = __builtin_bit_cast(bf16x8,
                *(const ushortx8*)(&sm.kv.Kt[kc * 16 + l16][32 + lhi * 8]));
            f32x4 z = fzero;
            z = __builtin_amdgcn_mfma_f32_16x16x32_bf16(aq0, b0, z, 0, 0, 0);
            z = __builtin_amdgcn_mfma_f32_16x16x32_bf16(aq1, b1, z, 0, 0, 0);
            sacc[kc] = z;
        }

        // ---- online softmax (row r lives in this lane's 16-lane family) ----
        float tmax[4];
#pragma unroll
        for (int r = 0; r < 4; ++r)
            tmax[r] = fmaxf(fmaxf(sacc[0][r], sacc[1][r]),
                            fmaxf(sacc[2][r], sacc[3][r]));
#pragma unroll
        for (int msk = 1; msk < 16; msk <<= 1) {
#pragma unroll
            for (int r = 0; r < 4; ++r)
                tmax[r] = fmaxf(tmax[r], __shfl_xor(tmax[r], msk, 64));
        }

        float corr[4], psum[4], pv[4][4];
#pragma unroll
        for (int r = 0; r < 4; ++r) {
            float mnew = fmaxf(m_r[r], tmax[r]);
            corr[r] = exp2f((m_r[r] - mnew) * LOG2E);
            m_r[r] = mnew;
            psum[r] = 0.f;
        }
#pragma unroll
        for (int kc = 0; kc < 4; ++kc) {
#pragma unroll
            for (int r = 0; r < 4; ++r) {
                float pp = exp2f((sacc[kc][r] - m_r[r]) * LOG2E);
                pv[kc][r] = pp;
                psum[r] += pp;
            }
        }
#pragma unroll
        for (int msk = 1; msk < 16; msk <<= 1) {
#pragma unroll
            for (int r = 0; r < 4; ++r)
                psum[r] += __shfl_xor(psum[r], msk, 64);
        }
#pragma unroll
        for (int r = 0; r < 4; ++r) l_r[r] = l_r[r] * corr[r] + psum[r];
#pragma unroll
        for (int dc = 0; dc < 4; ++dc) {
#pragma unroll
            for (int r = 0; r < 4; ++r) oacc[dc][r] *= corr[r];
        }

        // P (C-layout) -> LDS -> A-layout fragments
#pragma unroll
        for (int kc = 0; kc < 4; ++kc) {
#pragma unroll
            for (int r = 0; r < 4; ++r) {
                __hip_bfloat16 hb = __float2bfloat16(pv[kc][r]);
                Pt[wvid][lhi * 4 + r][kc * 16 + l16] =
                    __builtin_bit_cast(unsigned short, hb);
            }
        }
        bf16x8 pa0 = __builtin_bit_cast(bf16x8,
            *(const ushortx8*)(&Pt[wvid][l16][lhi * 8]));
        bf16x8 pa1 = __builtin_bit_cast(bf16x8,
            *(const ushortx8*)(&Pt[wvid][l16][32 + lhi * 8]));

        // O += P V
#pragma unroll
        for (int dc = 0; dc < 4; ++dc) {
            bf16x8 b0 = __builtin_bit_cast(bf16x8,
                *(const ushortx8*)(&sm.kv.Vt[dc * 16 + l16][lhi * 8]));
            bf16x8 b1 = __builtin_bit_cast(bf16x8,
                *(const ushortx8*)(&sm.kv.Vt[dc * 16 + l16][32 + lhi * 8]));
            oacc[dc] = __builtin_amdgcn_mfma_f32_16x16x32_bf16(pa0, b0, oacc[dc], 0, 0, 0);
            oacc[dc] = __builtin_amdgcn_mfma_f32_16x16x32_bf16(pa1, b1, oacc[dc], 0, 0, 0);
        }
        __syncthreads();
    }

    // epilogue: normalize, transpose via LDS, coalesced dual store
#pragma unroll
    for (int dc = 0; dc < 4; ++dc) {
#pragma unroll
        for (int r = 0; r < 4; ++r)
            sm.Ob[wvid * 16 + lhi * 4 + r][dc * 16 + l16] = oacc[dc][r] / l_r[r];
    }
    __syncthreads();

    const int d = t >> 2, qc = t & 3;
    size_t ob = (((size_t)(b * 64 + d)) * 2 + h) * 4096 + qt * 64 + qc * 16;
#pragma unroll
    for (int k0 = 0; k0 < 16; k0 += 4) {
        float4 vv;
        vv.x = sm.Ob[qc * 16 + k0 + 0][d];
        vv.y = sm.Ob[qc * 16 + k0 + 1][d];
        vv.z = sm.Ob[qc * 16 + k0 + 2][d];
        vv.w = sm.Ob[qc * 16 + k0 + 3][d];
        *(float4*)(out + ob + k0) = vv;
        *(float4*)(out + ob + OUT_HALF + k0) = vv;
    }
}

// ---------------------------------------------------------------------------
extern "C" void kernel_launch(void* const* d_in, const int* in_sizes, int n_in,
                              void* d_out, int out_size, void* d_ws, size_t ws_size,
                              hipStream_t stream) {
    const float* x  = (const float*)d_in[0];
    const float* wq = (const float*)d_in[1];
    const float* bq = (const float*)d_in[2];
    const float* wk = (const float*)d_in[3];
    const float* bk = (const float*)d_in[4];
    const float* wv = (const float*)d_in[5];
    const float* bv = (const float*)d_in[6];
    const float* pe = (const float*)d_in[7];
    float* out = (float*)d_out;

    char* ws = (char*)d_ws;
    float*    pet = (float*)ws;                                  // 2 MB
    ushort_t* qw  = (ushort_t*)(ws + (size_t)2  * 1024 * 1024);  // 4 MB
    ushort_t* kw  = (ushort_t*)(ws + (size_t)6  * 1024 * 1024);  // 4 MB
    ushort_t* vw  = (ushort_t*)(ws + (size_t)10 * 1024 * 1024);  // 4 MB

    hipLaunchKernelGGL(pet_kernel, dim3(1024), dim3(256), 0, stream, pe, pet);
    hipLaunchKernelGGL(proj_kernel, dim3(64, 4, 3), dim3(256), 0, stream,
                       x, wq, bq, wk, bk, wv, bv, pet, qw, kw, vw);
    hipLaunchKernelGGL(attn_kernel, dim3(64, 8), dim3(256), 0, stream,
                       qw, kw, vw, out);
}

// Round 2
// 153.696 us; speedup vs baseline: 1.5125x; 1.5125x over previous
//
#include <hip/hip_runtime.h>
#include <hip/hip_bf16.h>

typedef unsigned short ushort_t;
typedef unsigned short ushortx8 __attribute__((ext_vector_type(8)));
typedef __bf16        bf16x8   __attribute__((ext_vector_type(8)));
typedef float         f32x4    __attribute__((ext_vector_type(4)));

#define SCALE_QL (0.29730177875068026f * 1.4426950408889634f) /* 128^-.25 * log2e */
#define OUT_HALF 2097152               /* B*C*H*W elements */
#define NSPLIT   2
#define KT_SPLIT 32                    /* 64 kt tiles / NSPLIT */

static __device__ __forceinline__ float fexp2(float x) {
#if __has_builtin(__builtin_amdgcn_exp2f)
    return __builtin_amdgcn_exp2f(x);
#else
    float r; asm("v_exp_f32 %0, %1" : "=v"(r) : "v"(x)); return r;
#endif
}
static __device__ __forceinline__ unsigned cvtpk_bf16(float lo, float hi) {
    unsigned r;
    asm("v_cvt_pk_bf16_f32 %0, %1, %2" : "=v"(r) : "v"(lo), "v"(hi));
    return r;
}
static __device__ __forceinline__ void glds16(const void* g, void* l) {
    __builtin_amdgcn_global_load_lds(
        (const __attribute__((address_space(1))) unsigned int*)g,
        (__attribute__((address_space(3))) unsigned int*)l, 16, 0, 0);
}

// ---------------------------------------------------------------------------
// pe [n][d][h] f32  ->  pet [h][n][d] f32
__global__ __launch_bounds__(256) void pet_kernel(const float* __restrict__ pe,
                                                  float* __restrict__ pet) {
    int idx = blockIdx.x * 256 + threadIdx.x;
    if (idx >= 4096 * 64) return;
    float2 p2 = *(const float2*)(pe + (size_t)idx * 2);
    pet[idx]                      = p2.x;
    pet[(size_t)4096 * 64 + idx]  = p2.y;
}

// ---------------------------------------------------------------------------
// QKV projection. grid (64 ntile, 4 b, 3 proj), 256 thr.
// q,k -> token-major bf16 [bh][n][d]; v -> d-major bf16 [bh][d][n].
// q gets (+pe) * 128^-0.25 * log2(e) folded in (scores land in log2 domain).
__global__ __launch_bounds__(256) void proj_kernel(
    const float* __restrict__ x,
    const float* __restrict__ wq, const float* __restrict__ bq,
    const float* __restrict__ wk, const float* __restrict__ bk,
    const float* __restrict__ wv, const float* __restrict__ bv,
    const float* __restrict__ pet,
    ushort_t* __restrict__ qw, ushort_t* __restrict__ kw,
    ushort_t* __restrict__ vw)
{
    const int nt = blockIdx.x;
    const int b  = blockIdx.y;
    const int p  = blockIdx.z;         // 0=q 1=k 2=v
    const float* w    = (p == 0) ? wq : (p == 1) ? wk : wv;
    const float* bias = (p == 0) ? bq : (p == 1) ? bk : bv;

    __shared__ __align__(16) union { float xs[128][64]; float tr[128][65]; } sm;

    const int t = threadIdx.x;
    for (int f = t; f < 2048; f += 256) {
        int c = f >> 4, pos = (f & 15) << 2;
        *(float4*)(&sm.xs[c][pos]) =
            *(const float4*)(x + ((size_t)(b * 128 + c)) * 4096 + nt * 64 + pos);
    }
    __syncthreads();

    const int lane  = t & 63;
    const int wvid  = __builtin_amdgcn_readfirstlane(t >> 6);
    const int obase = wvid * 32;

    float acc[32];
#pragma unroll
    for (int i = 0; i < 32; ++i) acc[i] = bias[obase + i];

    for (int c0 = 0; c0 < 128; c0 += 16) {
        float xv[16];
#pragma unroll
        for (int cc = 0; cc < 16; ++cc) xv[cc] = sm.xs[c0 + cc][lane];
#pragma unroll
        for (int i = 0; i < 32; ++i) {
            const float* wrow = w + (size_t)(obase + i) * 128 + c0;
#pragma unroll
            for (int cc = 0; cc < 16; ++cc) acc[i] += wrow[cc] * xv[cc];
        }
    }

    if (p == 2) {
#pragma unroll
        for (int i = 0; i < 32; ++i) {
            int o = obase + i, h = o >> 6, d = o & 63;
            __hip_bfloat16 hb = __float2bfloat16(acc[i]);
            vw[(((size_t)(b * 2 + h)) * 64 + d) * 4096 + nt * 64 + lane] =
                __builtin_bit_cast(unsigned short, hb);
        }
        return;
    }

    __syncthreads();
#pragma unroll
    for (int i = 0; i < 32; ++i) sm.tr[obase + i][lane] = acc[i];
    __syncthreads();

    ushort_t* dst = (p == 0) ? qw : kw;
    const int n = t >> 2, oq = t & 3;
    const int h = oq >> 1, nglob = nt * 64 + n;
    const int dbase = (oq & 1) * 32;
    ushortx8 u[4];
#pragma unroll
    for (int i = 0; i < 32; ++i) {
        float v = sm.tr[oq * 32 + i][n];
        if (p == 0)
            v = (v + pet[((size_t)h * 4096 + nglob) * 64 + dbase + i]) * SCALE_QL;
        __hip_bfloat16 hb = __float2bfloat16(v);
        u[i >> 3][i & 7] = __builtin_bit_cast(unsigned short, hb);
    }
    size_t base = (((size_t)(b * 2 + h)) * 4096 + nglob) * 64 + dbase;
#pragma unroll
    for (int j = 0; j < 4; ++j) *(ushortx8*)(dst + base + j * 8) = u[j];
}

// ---------------------------------------------------------------------------
// Flash attention, swapped-operand (S^T = K*Q) so softmax is lane-local.
// grid (64 qtile, 8 bh, NSPLIT), 256 thr (4 waves x 16 q-rows).
// Writes unnormalized O partials + (m,l) per q-row for the combine pass.
__global__ __launch_bounds__(256) void attn_kernel(
    const ushort_t* __restrict__ qw, const ushort_t* __restrict__ kw,
    const ushort_t* __restrict__ vw, float* __restrict__ opart,
    float* __restrict__ mlpart)
{
    const int qt = blockIdx.x, bh = blockIdx.y, sp = blockIdx.z;
    const int t = threadIdx.x, lane = t & 63;
    const int wvid = t >> 6;
    const int l16 = lane & 15, lhi = lane >> 4;

    __shared__ __align__(16) ushort_t Kt[64 * 64];   // [key][d]  xor-swizzled
    __shared__ __align__(16) ushort_t Vt[64 * 64];   // [d][key]  xor-swizzled
    __shared__ unsigned PtW[4][32][17];              // per-wave P exchange

    // Q fragment (B operand): col = q = l16, k = d chunk lhi*8 (+32)
    const ushort_t* qp =
        qw + (((size_t)bh * 4096) + qt * 64 + wvid * 16 + l16) * 64 + lhi * 8;
    const bf16x8 bq0 = __builtin_bit_cast(bf16x8, *(const ushortx8*)(qp));
    const bf16x8 bq1 = __builtin_bit_cast(bf16x8, *(const ushortx8*)(qp + 32));

    const ushort_t* kgb = kw + ((size_t)bh * 4096) * 64;
    const ushort_t* vgb = vw + ((size_t)bh * 64) * 4096;

    // staging: lane l covers LDS row rb+i*8+(l>>3), 16B-chunk l&7; the global
    // source column is pre-XOR-swizzled so LDS slot c holds chunk c^(row&7).
    const int sub = lane >> 3, c7 = lane & 7;
    const int rb  = wvid * 16;
    const int swz = (c7 ^ sub) << 3;                 // ushort offset
    const size_t koff0 = (size_t)(rb + sub) * 64 + swz;
    const size_t koff1 = (size_t)(rb + 8 + sub) * 64 + swz;
    const size_t voff0 = (size_t)(rb + sub) * 4096 + swz;
    const size_t voff1 = (size_t)(rb + 8 + sub) * 4096 + swz;
    ushort_t* kd0 = Kt + rb * 64;
    ushort_t* kd1 = Kt + (rb + 8) * 64;
    ushort_t* vd0 = Vt + rb * 64;
    ushort_t* vd1 = Vt + (rb + 8) * 64;

    // swizzled read offsets: chunk lhi of row (16c+l16) sits at byte xs0
    const int xs0 = (lhi ^ (l16 & 7)) << 4;
    const int xs1 = xs0 ^ 64;
    const char* ktb = (const char*)Kt;
    const char* vtb = (const char*)Vt;

    float m = -1e30f, lsum = 0.f;
    f32x4 oacc[4];
    const f32x4 fz = {0.f, 0.f, 0.f, 0.f};
#pragma unroll
    for (int dc = 0; dc < 4; ++dc) oacc[dc] = fz;

    const int kt0 = sp * KT_SPLIT;
    for (int kt = kt0; kt < kt0 + KT_SPLIT; ++kt) {
        const ushort_t* kg = kgb + (size_t)kt * 4096;
        const ushort_t* vg = vgb + (size_t)kt * 64;
        glds16(kg + koff0, kd0);
        glds16(kg + koff1, kd1);
        glds16(vg + voff0, vd0);
        glds16(vg + voff1, vd1);
        __syncthreads();

        // S^T tile: lane holds S[key = kc*16 + lhi*4 + r][q = l16]
        f32x4 sacc[4];
#pragma unroll
        for (int kc = 0; kc < 4; ++kc) {
            const int row = kc * 16 + l16;
            bf16x8 ka0 = __builtin_bit_cast(bf16x8,
                *(const ushortx8*)(ktb + row * 128 + xs0));
            bf16x8 ka1 = __builtin_bit_cast(bf16x8,
                *(const ushortx8*)(ktb + row * 128 + xs1));
            f32x4 z = fz;
            z = __builtin_amdgcn_mfma_f32_16x16x32_bf16(ka0, bq0, z, 0, 0, 0);
            z = __builtin_amdgcn_mfma_f32_16x16x32_bf16(ka1, bq1, z, 0, 0, 0);
            sacc[kc] = z;
        }

        // ---- lane-local online softmax (scores already in log2 domain) ----
        float smax = sacc[0][0];
#pragma unroll
        for (int kc = 0; kc < 4; ++kc)
#pragma unroll
            for (int r = 0; r < 4; ++r) smax = fmaxf(smax, sacc[kc][r]);
        smax = fmaxf(smax, __shfl_xor(smax, 16, 64));
        smax = fmaxf(smax, __shfl_xor(smax, 32, 64));

        float mnew = fmaxf(m, smax);
        float corr = fexp2(m - mnew);
        m = mnew;
        float p[16], psum = 0.f;
#pragma unroll
        for (int kc = 0; kc < 4; ++kc)
#pragma unroll
            for (int r = 0; r < 4; ++r) {
                float pp = fexp2(sacc[kc][r] - m);
                p[kc * 4 + r] = pp;
                psum += pp;
            }
        psum += __shfl_xor(psum, 16, 64);
        psum += __shfl_xor(psum, 32, 64);
        lsum = lsum * corr + psum;
#pragma unroll
        for (int dc = 0; dc < 4; ++dc) oacc[dc] *= corr;

        // ---- P exchange: C-layout -> B-fragment via per-wave padded LDS ----
#pragma unroll
        for (int kc = 0; kc < 4; ++kc)
#pragma unroll
            for (int rp = 0; rp < 2; ++rp)
                PtW[wvid][8 * kc + 2 * lhi + rp][l16] =
                    cvtpk_bf16(p[kc * 4 + 2 * rp], p[kc * 4 + 2 * rp + 1]);

        unsigned pb0i[4], pb1i[4];
#pragma unroll
        for (int j = 0; j < 4; ++j) {
            pb0i[j] = PtW[wvid][4 * lhi + j][l16];
            pb1i[j] = PtW[wvid][16 + 4 * lhi + j][l16];
        }
        bf16x8 pb0 = __builtin_bit_cast(bf16x8, *(ushortx8*)pb0i);
        bf16x8 pb1 = __builtin_bit_cast(bf16x8, *(ushortx8*)pb1i);

        // ---- O^T += V^T P^T : lane ends with O[q=l16][d = dc*16+lhi*4+r] ----
#pragma unroll
        for (int dc = 0; dc < 4; ++dc) {
            const int row = dc * 16 + l16;
            bf16x8 va0 = __builtin_bit_cast(bf16x8,
                *(const ushortx8*)(vtb + row * 128 + xs0));
            bf16x8 va1 = __builtin_bit_cast(bf16x8,
                *(const ushortx8*)(vtb + row * 128 + xs1));
            oacc[dc] = __builtin_amdgcn_mfma_f32_16x16x32_bf16(va0, pb0, oacc[dc], 0, 0, 0);
            oacc[dc] = __builtin_amdgcn_mfma_f32_16x16x32_bf16(va1, pb1, oacc[dc], 0, 0, 0);
        }
        __syncthreads();
    }

    // partial epilogue: lane-major coalesced dump; combine kernel unpicks it
    const int pidx = (qt * 8 + bh) * NSPLIT + sp;
    float* op = opart + (size_t)pidx * 4096 + wvid * 1024 + lane * 16;
#pragma unroll
    for (int dc = 0; dc < 4; ++dc) *(f32x4*)(op + dc * 4) = oacc[dc];
    if (lhi == 0) {
        float* mlo = mlpart + (size_t)pidx * 128 + wvid * 32 + l16;
        mlo[0]  = m;
        mlo[16] = lsum;
    }
}

// ---------------------------------------------------------------------------
// Combine NSPLIT partials, normalize, transpose, write out twice.
__global__ __launch_bounds__(256) void combine_kernel(
    const float* __restrict__ opart, const float* __restrict__ mlpart,
    float* __restrict__ out)
{
    const int qt = blockIdx.x, bh = blockIdx.y;
    const int b = bh >> 1, h = bh & 1;
    const int t = threadIdx.x, lane = t & 63, w = t >> 6;
    const int l16 = lane & 15, lhi = lane >> 4;
    __shared__ __align__(16) float smT[64][68];

    const int p0 = (qt * 8 + bh) * NSPLIT;
    const float* mlb = mlpart + (size_t)p0 * 128 + w * 32 + l16;
    float m1 = mlb[0],   l1 = mlb[16];
    float m2 = mlb[128], l2 = mlb[128 + 16];
    float M  = fmaxf(m1, m2);
    float c1 = fexp2(m1 - M), c2 = fexp2(m2 - M);
    float inv = 1.f / (l1 * c1 + l2 * c2);
    c1 *= inv; c2 *= inv;

    const float* o1 = opart + (size_t)p0 * 4096 + w * 1024 + lane * 16;
    const float* o2 = o1 + 4096;
#pragma unroll
    for (int dc = 0; dc < 4; ++dc) {
        f32x4 a  = *(const f32x4*)(o1 + dc * 4);
        f32x4 bb = *(const f32x4*)(o2 + dc * 4);
        f32x4 ov = a * c1 + bb * c2;
#pragma unroll
        for (int r = 0; r < 4; ++r)
            smT[dc * 16 + lhi * 4 + r][w * 16 + l16] = ov[r];
    }
    __syncthreads();

    const int d = t >> 2, qq = t & 3;
    size_t ob = (((size_t)(b * 64 + d)) * 2 + h) * 4096 + qt * 64 + qq * 16;
#pragma unroll
    for (int k0 = 0; k0 < 16; k0 += 4) {
        f32x4 vv = *(const f32x4*)(&smT[d][qq * 16 + k0]);
        *(f32x4*)(out + ob + k0) = vv;
        *(f32x4*)(out + ob + OUT_HALF + k0) = vv;
    }
}

// ---------------------------------------------------------------------------
extern "C" void kernel_launch(void* const* d_in, const int* in_sizes, int n_in,
                              void* d_out, int out_size, void* d_ws, size_t ws_size,
                              hipStream_t stream) {
    const float* x  = (const float*)d_in[0];
    const float* wq = (const float*)d_in[1];
    const float* bq = (const float*)d_in[2];
    const float* wk = (const float*)d_in[3];
    const float* bk = (const float*)d_in[4];
    const float* wv = (const float*)d_in[5];
    const float* bv = (const float*)d_in[6];
    const float* pe = (const float*)d_in[7];
    float* out = (float*)d_out;

    char* ws = (char*)d_ws;
    float*    pet   = (float*)ws;                                   // 2 MB
    ushort_t* qw    = (ushort_t*)(ws + (size_t)2  * 1024 * 1024);   // 4 MB
    ushort_t* kw    = (ushort_t*)(ws + (size_t)6  * 1024 * 1024);   // 4 MB
    ushort_t* vw    = (ushort_t*)(ws + (size_t)10 * 1024 * 1024);   // 4 MB
    float*    opart = (float*)(ws + (size_t)14 * 1024 * 1024);      // 16 MB
    float*    mlprt = (float*)(ws + (size_t)30 * 1024 * 1024);      // 0.5 MB

    hipLaunchKernelGGL(pet_kernel, dim3(1024), dim3(256), 0, stream, pe, pet);
    hipLaunchKernelGGL(proj_kernel, dim3(64, 4, 3), dim3(256), 0, stream,
                       x, wq, bq, wk, bk, wv, bv, pet, qw, kw, vw);
    hipLaunchKernelGGL(attn_kernel, dim3(64, 8, NSPLIT), dim3(256), 0, stream,
                       qw, kw, vw, opart, mlprt);
    hipLaunchKernelGGL(combine_kernel, dim3(64, 8), dim3(256), 0, stream,
                       opart, mlprt, out);
}

// Round 3
// 101.730 us; speedup vs baseline: 2.2851x; 1.5108x over previous
//
#include <hip/hip_runtime.h>
#include <hip/hip_bf16.h>

typedef unsigned short ushort_t;
typedef unsigned short ushortx8 __attribute__((ext_vector_type(8)));
typedef unsigned short ushortx4 __attribute__((ext_vector_type(4)));
typedef __bf16        bf16x8   __attribute__((ext_vector_type(8)));
typedef float         f32x4    __attribute__((ext_vector_type(4)));

#define SCALE_QL (0.29730177875068026f * 1.4426950408889634f) /* 128^-.25 * log2e */
#define OUT_HALF 2097152               /* B*C*H*W elements */
#define NSPLIT   2
#define KT_SPLIT 32                    /* 64 kt tiles / NSPLIT */

static __device__ __forceinline__ float fexp2(float x) {
#if __has_builtin(__builtin_amdgcn_exp2f)
    return __builtin_amdgcn_exp2f(x);
#else
    float r; asm("v_exp_f32 %0, %1" : "=v"(r) : "v"(x)); return r;
#endif
}
static __device__ __forceinline__ unsigned cvtpk_bf16(float lo, float hi) {
    unsigned r;
    asm("v_cvt_pk_bf16_f32 %0, %1, %2" : "=v"(r) : "v"(lo), "v"(hi));
    return r;
}
static __device__ __forceinline__ ushort_t bf16u(float f) {
    __hip_bfloat16 h = __float2bfloat16(f);
    return __builtin_bit_cast(ushort_t, h);
}
static __device__ __forceinline__ void glds16(const void* g, void* l) {
    __builtin_amdgcn_global_load_lds(
        (const __attribute__((address_space(1))) unsigned int*)g,
        (__attribute__((address_space(3))) unsigned int*)l, 16, 0, 0);
}

// ---------------------------------------------------------------------------
// prep: pe [n][d][h] -> pet [h][n][d] f32;  wq/wk/wv f32 -> wb bf16 with
// row-local 16B-chunk xor swizzle (chunk ^= o&15) baked in.
__global__ __launch_bounds__(256) void prep_kernel(
    const float* __restrict__ pe,
    const float* __restrict__ wq, const float* __restrict__ wk,
    const float* __restrict__ wv,
    float* __restrict__ pet, ushort_t* __restrict__ wb)
{
    const int bid = blockIdx.x, t = threadIdx.x;
    if (bid < 1024) {
        int idx = bid * 256 + t;
        float2 p2 = *(const float2*)(pe + (size_t)idx * 2);
        pet[idx]                     = p2.x;
        pet[(size_t)4096 * 64 + idx] = p2.y;
        return;
    }
    const int b2 = bid - 1024;                 // 0..23
    const int p  = b2 >> 3;
    const float* w = (p == 0) ? wq : (p == 1) ? wk : wv;
    const int cid = (b2 & 7) * 256 + t;        // 16B-chunk id 0..2047
    const int o = cid >> 4, chunk = cid & 15;
    float4 f0 = *(const float4*)(w + o * 128 + chunk * 8);
    float4 f1 = *(const float4*)(w + o * 128 + chunk * 8 + 4);
    ushortx8 u;
    u[0] = bf16u(f0.x); u[1] = bf16u(f0.y); u[2] = bf16u(f0.z); u[3] = bf16u(f0.w);
    u[4] = bf16u(f1.x); u[5] = bf16u(f1.y); u[6] = bf16u(f1.z); u[7] = bf16u(f1.w);
    *(ushortx8*)(wb + p * 16384 + o * 128 + ((chunk ^ (o & 15)) << 3)) = u;
}

// ---------------------------------------------------------------------------
// x [b][c=128][n] f32 -> xtb [b][n][c=128] bf16, chunk-swizzled per row.
__global__ __launch_bounds__(256) void xt_kernel(const float* __restrict__ x,
                                                 ushort_t* __restrict__ xtb)
{
    const int nt = blockIdx.x, b = blockIdx.y;
    __shared__ __align__(16) ushort_t xs[128][68];
    const int t = threadIdx.x;
    const int cg = t >> 4, n0 = (t & 15) * 4;
#pragma unroll
    for (int i = 0; i < 8; ++i) {
        int c = i * 16 + cg;
        float4 f = *(const float4*)(x + ((size_t)(b * 128 + c)) * 4096 + nt * 64 + n0);
        ushortx4 u;
        u[0] = bf16u(f.x); u[1] = bf16u(f.y); u[2] = bf16u(f.z); u[3] = bf16u(f.w);
        *(ushortx4*)(&xs[c][n0]) = u;
    }
    __syncthreads();
    const int n = t >> 2;
    ushort_t* dst = xtb + ((size_t)b * 4096 + nt * 64 + n) * 128;
#pragma unroll
    for (int j = 0; j < 4; ++j) {
        int chunk = (t & 3) * 4 + j;
        ushortx8 u;
#pragma unroll
        for (int e = 0; e < 8; ++e) u[e] = xs[chunk * 8 + e][n];
        *(ushortx8*)(dst + ((chunk ^ (n & 15)) << 3)) = u;
    }
}

// ---------------------------------------------------------------------------
// MFMA projection: per block 128 outputs x 128 tokens, K=128.
// grid (32 ntile, 4 b, 3 p), 256 thr (4 waves, each 32 output rows).
__global__ __launch_bounds__(256, 2) void proj_kernel(
    const ushort_t* __restrict__ xtb, const ushort_t* __restrict__ wb,
    const float* __restrict__ bq, const float* __restrict__ bk,
    const float* __restrict__ bv, const float* __restrict__ pet,
    ushort_t* __restrict__ qw, ushort_t* __restrict__ kw,
    ushort_t* __restrict__ vw)
{
    const int ntl = blockIdx.x;        // 128-token tile
    const int b = blockIdx.y, p = blockIdx.z;
    __shared__ __align__(16) ushort_t xt[16384];   // [n128][c128] swizzled
    __shared__ __align__(16) ushort_t wt[16384];   // [o128][c128] swizzled
    const int t = threadIdx.x, lane = t & 63;
    const int wv_ = __builtin_amdgcn_readfirstlane(t >> 6);
    const int l16 = lane & 15, lhi = lane >> 4;

    const ushort_t* xsrc = xtb + ((size_t)b * 4096 + ntl * 128) * 128;
    const ushort_t* wsrc = wb + p * 16384;
#pragma unroll
    for (int j = 0; j < 8; ++j) {
        int row = wv_ * 32 + j * 4;
        glds16(xsrc + row * 128 + lane * 8, xt + row * 128);
        glds16(wsrc + row * 128 + lane * 8, wt + row * 128);
    }

    const float* bias = (p == 0) ? bq : (p == 1) ? bk : bv;
    f32x4 bias4[2];
    bias4[0] = *(const f32x4*)(bias + wv_ * 32 + lhi * 4);
    bias4[1] = *(const f32x4*)(bias + wv_ * 32 + 16 + lhi * 4);
    f32x4 acc[2][8];
#pragma unroll
    for (int mf = 0; mf < 2; ++mf)
#pragma unroll
        for (int nf = 0; nf < 8; ++nf) acc[mf][nf] = bias4[mf];

    __syncthreads();

    const char* xbp = (const char*)xt;
    const char* wbp = (const char*)wt;
#pragma unroll
    for (int ks = 0; ks < 4; ++ks) {
        bf16x8 af[2];
#pragma unroll
        for (int mf = 0; mf < 2; ++mf) {
            int row = wv_ * 32 + mf * 16 + l16;
            af[mf] = __builtin_bit_cast(bf16x8, *(const ushortx8*)(
                wbp + row * 256 + ((((ks * 4 + lhi) ^ l16) & 15) << 4)));
        }
#pragma unroll
        for (int nf = 0; nf < 8; ++nf) {
            int row = nf * 16 + l16;
            bf16x8 bfr = __builtin_bit_cast(bf16x8, *(const ushortx8*)(
                xbp + row * 256 + ((((ks * 4 + lhi) ^ l16) & 15) << 4)));
            acc[0][nf] = __builtin_amdgcn_mfma_f32_16x16x32_bf16(af[0], bfr, acc[0][nf], 0, 0, 0);
            acc[1][nf] = __builtin_amdgcn_mfma_f32_16x16x32_bf16(af[1], bfr, acc[1][nf], 0, 0, 0);
        }
    }

    const int nbase = ntl * 128;
    if (p == 2) {                      // V -> d-major [bh][d][n]
#pragma unroll
        for (int mf = 0; mf < 2; ++mf) {
            int o = wv_ * 32 + mf * 16 + lhi * 4;
            int h = o >> 6, d = o & 63;
            ushort_t* vb = vw + (((size_t)(b * 2 + h) * 64 + d)) * 4096 + nbase + l16;
#pragma unroll
            for (int nf = 0; nf < 8; ++nf)
#pragma unroll
                for (int r = 0; r < 4; ++r)
                    vb[(size_t)r * 4096 + nf * 16] = bf16u(acc[mf][nf][r]);
        }
    } else if (p == 0) {               // Q: +pe, *scale, token-major
#pragma unroll
        for (int mf = 0; mf < 2; ++mf) {
            int o = wv_ * 32 + mf * 16 + lhi * 4;
            int h = o >> 6, d = o & 63;
#pragma unroll
            for (int nf = 0; nf < 8; ++nf) {
                int n = nbase + nf * 16 + l16;
                f32x4 pe4 = *(const f32x4*)(pet + ((size_t)h * 4096 + n) * 64 + d);
                f32x4 q4 = (acc[mf][nf] + pe4) * SCALE_QL;
                ushortx4 s;
                s[0] = bf16u(q4[0]); s[1] = bf16u(q4[1]);
                s[2] = bf16u(q4[2]); s[3] = bf16u(q4[3]);
                *(ushortx4*)(qw + ((size_t)(b * 2 + h) * 4096 + n) * 64 + d) = s;
            }
        }
    } else {                           // K: token-major
#pragma unroll
        for (int mf = 0; mf < 2; ++mf) {
            int o = wv_ * 32 + mf * 16 + lhi * 4;
            int h = o >> 6, d = o & 63;
#pragma unroll
            for (int nf = 0; nf < 8; ++nf) {
                int n = nbase + nf * 16 + l16;
                f32x4 k4 = acc[mf][nf];
                ushortx4 s;
                s[0] = bf16u(k4[0]); s[1] = bf16u(k4[1]);
                s[2] = bf16u(k4[2]); s[3] = bf16u(k4[3]);
                *(ushortx4*)(kw + ((size_t)(b * 2 + h) * 4096 + n) * 64 + d) = s;
            }
        }
    }
}

// ---------------------------------------------------------------------------
// Flash attention, swapped-operand (S^T = K*Q) so softmax is lane-local.
// grid (64 qtile, 8 bh, NSPLIT), 256 thr (4 waves x 16 q-rows).
__global__ __launch_bounds__(256) void attn_kernel(
    const ushort_t* __restrict__ qw, const ushort_t* __restrict__ kw,
    const ushort_t* __restrict__ vw, float* __restrict__ opart,
    float* __restrict__ mlpart)
{
    const int qt = blockIdx.x, bh = blockIdx.y, sp = blockIdx.z;
    const int t = threadIdx.x, lane = t & 63;
    const int wvid = t >> 6;
    const int l16 = lane & 15, lhi = lane >> 4;

    __shared__ __align__(16) ushort_t Kt[64 * 64];   // [key][d]  xor-swizzled
    __shared__ __align__(16) ushort_t Vt[64 * 64];   // [d][key]  xor-swizzled
    __shared__ unsigned PtW[4][32][17];              // per-wave P exchange

    const ushort_t* qp =
        qw + (((size_t)bh * 4096) + qt * 64 + wvid * 16 + l16) * 64 + lhi * 8;
    const bf16x8 bq0 = __builtin_bit_cast(bf16x8, *(const ushortx8*)(qp));
    const bf16x8 bq1 = __builtin_bit_cast(bf16x8, *(const ushortx8*)(qp + 32));

    const ushort_t* kgb = kw + ((size_t)bh * 4096) * 64;
    const ushort_t* vgb = vw + ((size_t)bh * 64) * 4096;

    const int sub = lane >> 3, c7 = lane & 7;
    const int rb  = wvid * 16;
    const int swz = (c7 ^ sub) << 3;
    const size_t koff0 = (size_t)(rb + sub) * 64 + swz;
    const size_t koff1 = (size_t)(rb + 8 + sub) * 64 + swz;
    const size_t voff0 = (size_t)(rb + sub) * 4096 + swz;
    const size_t voff1 = (size_t)(rb + 8 + sub) * 4096 + swz;
    ushort_t* kd0 = Kt + rb * 64;
    ushort_t* kd1 = Kt + (rb + 8) * 64;
    ushort_t* vd0 = Vt + rb * 64;
    ushort_t* vd1 = Vt + (rb + 8) * 64;

    const int xs0 = (lhi ^ (l16 & 7)) << 4;
    const int xs1 = xs0 ^ 64;
    const char* ktb = (const char*)Kt;
    const char* vtb = (const char*)Vt;

    float m = -1e30f, lsum = 0.f;
    f32x4 oacc[4];
    const f32x4 fz = {0.f, 0.f, 0.f, 0.f};
#pragma unroll
    for (int dc = 0; dc < 4; ++dc) oacc[dc] = fz;

    const int kt0 = sp * KT_SPLIT;
    for (int kt = kt0; kt < kt0 + KT_SPLIT; ++kt) {
        const ushort_t* kg = kgb + (size_t)kt * 4096;
        const ushort_t* vg = vgb + (size_t)kt * 64;
        glds16(kg + koff0, kd0);
        glds16(kg + koff1, kd1);
        glds16(vg + voff0, vd0);
        glds16(vg + voff1, vd1);
        __syncthreads();

        f32x4 sacc[4];
#pragma unroll
        for (int kc = 0; kc < 4; ++kc) {
            const int row = kc * 16 + l16;
            bf16x8 ka0 = __builtin_bit_cast(bf16x8,
                *(const ushortx8*)(ktb + row * 128 + xs0));
            bf16x8 ka1 = __builtin_bit_cast(bf16x8,
                *(const ushortx8*)(ktb + row * 128 + xs1));
            f32x4 z = fz;
            z = __builtin_amdgcn_mfma_f32_16x16x32_bf16(ka0, bq0, z, 0, 0, 0);
            z = __builtin_amdgcn_mfma_f32_16x16x32_bf16(ka1, bq1, z, 0, 0, 0);
            sacc[kc] = z;
        }

        float smax = sacc[0][0];
#pragma unroll
        for (int kc = 0; kc < 4; ++kc)
#pragma unroll
            for (int r = 0; r < 4; ++r) smax = fmaxf(smax, sacc[kc][r]);
        smax = fmaxf(smax, __shfl_xor(smax, 16, 64));
        smax = fmaxf(smax, __shfl_xor(smax, 32, 64));

        float mnew = fmaxf(m, smax);
        float corr = fexp2(m - mnew);
        m = mnew;
        float p[16], psum = 0.f;
#pragma unroll
        for (int kc = 0; kc < 4; ++kc)
#pragma unroll
            for (int r = 0; r < 4; ++r) {
                float pp = fexp2(sacc[kc][r] - m);
                p[kc * 4 + r] = pp;
                psum += pp;
            }
        psum += __shfl_xor(psum, 16, 64);
        psum += __shfl_xor(psum, 32, 64);
        lsum = lsum * corr + psum;
#pragma unroll
        for (int dc = 0; dc < 4; ++dc) oacc[dc] *= corr;

#pragma unroll
        for (int kc = 0; kc < 4; ++kc)
#pragma unroll
            for (int rp = 0; rp < 2; ++rp)
                PtW[wvid][8 * kc + 2 * lhi + rp][l16] =
                    cvtpk_bf16(p[kc * 4 + 2 * rp], p[kc * 4 + 2 * rp + 1]);

        unsigned pb0i[4], pb1i[4];
#pragma unroll
        for (int j = 0; j < 4; ++j) {
            pb0i[j] = PtW[wvid][4 * lhi + j][l16];
            pb1i[j] = PtW[wvid][16 + 4 * lhi + j][l16];
        }
        bf16x8 pb0 = __builtin_bit_cast(bf16x8, *(ushortx8*)pb0i);
        bf16x8 pb1 = __builtin_bit_cast(bf16x8, *(ushortx8*)pb1i);

#pragma unroll
        for (int dc = 0; dc < 4; ++dc) {
            const int row = dc * 16 + l16;
            bf16x8 va0 = __builtin_bit_cast(bf16x8,
                *(const ushortx8*)(vtb + row * 128 + xs0));
            bf16x8 va1 = __builtin_bit_cast(bf16x8,
                *(const ushortx8*)(vtb + row * 128 + xs1));
            oacc[dc] = __builtin_amdgcn_mfma_f32_16x16x32_bf16(va0, pb0, oacc[dc], 0, 0, 0);
            oacc[dc] = __builtin_amdgcn_mfma_f32_16x16x32_bf16(va1, pb1, oacc[dc], 0, 0, 0);
        }
        __syncthreads();
    }

    const int pidx = (qt * 8 + bh) * NSPLIT + sp;
    float* op = opart + (size_t)pidx * 4096 + wvid * 1024 + lane * 16;
#pragma unroll
    for (int dc = 0; dc < 4; ++dc) *(f32x4*)(op + dc * 4) = oacc[dc];
    if (lhi == 0) {
        float* mlo = mlpart + (size_t)pidx * 128 + wvid * 32 + l16;
        mlo[0]  = m;
        mlo[16] = lsum;
    }
}

// ---------------------------------------------------------------------------
// Combine NSPLIT partials, normalize, transpose, write out twice.
__global__ __launch_bounds__(256) void combine_kernel(
    const float* __restrict__ opart, const float* __restrict__ mlpart,
    float* __restrict__ out)
{
    const int qt = blockIdx.x, bh = blockIdx.y;
    const int b = bh >> 1, h = bh & 1;
    const int t = threadIdx.x, lane = t & 63, w = t >> 6;
    const int l16 = lane & 15, lhi = lane >> 4;
    __shared__ __align__(16) float smT[64][68];

    const int p0 = (qt * 8 + bh) * NSPLIT;
    const float* mlb = mlpart + (size_t)p0 * 128 + w * 32 + l16;
    float m1 = mlb[0],   l1 = mlb[16];
    float m2 = mlb[128], l2 = mlb[128 + 16];
    float M  = fmaxf(m1, m2);
    float c1 = fexp2(m1 - M), c2 = fexp2(m2 - M);
    float inv = 1.f / (l1 * c1 + l2 * c2);
    c1 *= inv; c2 *= inv;

    const float* o1 = opart + (size_t)p0 * 4096 + w * 1024 + lane * 16;
    const float* o2 = o1 + 4096;
#pragma unroll
    for (int dc = 0; dc < 4; ++dc) {
        f32x4 a  = *(const f32x4*)(o1 + dc * 4);
        f32x4 bb = *(const f32x4*)(o2 + dc * 4);
        f32x4 ov = a * c1 + bb * c2;
#pragma unroll
        for (int r = 0; r < 4; ++r)
            smT[dc * 16 + lhi * 4 + r][w * 16 + l16] = ov[r];
    }
    __syncthreads();

    const int d = t >> 2, qq = t & 3;
    size_t ob = (((size_t)(b * 64 + d)) * 2 + h) * 4096 + qt * 64 + qq * 16;
#pragma unroll
    for (int k0 = 0; k0 < 16; k0 += 4) {
        f32x4 vv = *(const f32x4*)(&smT[d][qq * 16 + k0]);
        *(f32x4*)(out + ob + k0) = vv;
        *(f32x4*)(out + ob + OUT_HALF + k0) = vv;
    }
}

// ---------------------------------------------------------------------------
extern "C" void kernel_launch(void* const* d_in, const int* in_sizes, int n_in,
                              void* d_out, int out_size, void* d_ws, size_t ws_size,
                              hipStream_t stream) {
    const float* x  = (const float*)d_in[0];
    const float* wq = (const float*)d_in[1];
    const float* bq = (const float*)d_in[2];
    const float* wk = (const float*)d_in[3];
    const float* bk = (const float*)d_in[4];
    const float* wv = (const float*)d_in[5];
    const float* bv = (const float*)d_in[6];
    const float* pe = (const float*)d_in[7];
    float* out = (float*)d_out;

    char* ws = (char*)d_ws;
    float*    pet   = (float*)ws;                                   // 2 MB
    ushort_t* qw    = (ushort_t*)(ws + (size_t)2  * 1024 * 1024);   // 4 MB
    ushort_t* kw    = (ushort_t*)(ws + (size_t)6  * 1024 * 1024);   // 4 MB
    ushort_t* vw    = (ushort_t*)(ws + (size_t)10 * 1024 * 1024);   // 4 MB
    float*    opart = (float*)(ws + (size_t)14 * 1024 * 1024);      // 16 MB (attn)
    ushort_t* xtb   = (ushort_t*)(ws + (size_t)14 * 1024 * 1024);   // 4 MB (proj, aliases opart)
    float*    mlprt = (float*)(ws + (size_t)30 * 1024 * 1024);      // 0.5 MB (attn)
    ushort_t* wb    = (ushort_t*)(ws + (size_t)30 * 1024 * 1024);   // 96 KB (proj, aliases mlprt)

    hipLaunchKernelGGL(prep_kernel, dim3(1048), dim3(256), 0, stream,
                       pe, wq, wk, wv, pet, wb);
    hipLaunchKernelGGL(xt_kernel, dim3(64, 4), dim3(256), 0, stream, x, xtb);
    hipLaunchKernelGGL(proj_kernel, dim3(32, 4, 3), dim3(256), 0, stream,
                       xtb, wb, bq, bk, bv, pet, qw, kw, vw);
    hipLaunchKernelGGL(attn_kernel, dim3(64, 8, NSPLIT), dim3(256), 0, stream,
                       qw, kw, vw, opart, mlprt);
    hipLaunchKernelGGL(combine_kernel, dim3(64, 8), dim3(256), 0, stream,
                       opart, mlprt, out);
}